// Round 7
// baseline (302.706 us; speedup 1.0000x reference)
//
#include <hip/hip_runtime.h>
#include <cstdint>

#define BB 2
#define SS 2048
#define DD 2048
#define HH 16
#define HDIM 128
#define MM (BB * SS)  // 4096

typedef __attribute__((ext_vector_type(8))) short bf16x8;
typedef __attribute__((ext_vector_type(4))) short bf16x4;
typedef __attribute__((ext_vector_type(4))) float f32x4;
typedef __attribute__((ext_vector_type(16))) float f32x16;

__device__ inline short f2bf(float f) {
  union { float f; unsigned u; } v; v.f = f;
  unsigned r = v.u + 0x7FFFu + ((v.u >> 16) & 1u);
  return (short)(r >> 16);
}
__device__ inline float bf2f(short s) {
  union { float f; unsigned u; } v;
  v.u = ((unsigned)(unsigned short)s) << 16;
  return v.f;
}
__device__ inline float asf(int u) { union { int i; float f; } v; v.i = u; return v.f; }
__device__ inline int asi(float f) { union { float f; int i; } v; v.f = f; return v.i; }

__device__ inline unsigned cvtpk_bf16(float lo, float hi) {
  unsigned r;
  asm("v_cvt_pk_bf16_f32 %0, %1, %2" : "=v"(r) : "v"(lo), "v"(hi));
  return r;
}

__device__ inline void gll16(const void* g, void* l) {
  __builtin_amdgcn_global_load_lds(
      (const __attribute__((address_space(1))) void*)g,
      (__attribute__((address_space(3))) void*)l, 16, 0, 0);
}

// ---------------- cast fp32 -> bf16 ----------------
__global__ __launch_bounds__(256) void cast_bf16_kernel(
    const float* __restrict__ x, short* __restrict__ y, int n4) {
  int i = blockIdx.x * 256 + threadIdx.x;
  if (i >= n4) return;
  float4 v = reinterpret_cast<const float4*>(x)[i];
  bf16x4 o;
  o[0] = f2bf(v.x); o[1] = f2bf(v.y); o[2] = f2bf(v.z); o[3] = f2bf(v.w);
  reinterpret_cast<bf16x4*>(y)[i] = o;
}

// ---------------- all 4 weight transposes in ONE launch (z = 0..3) ----------------
__global__ __launch_bounds__(256) void transpose4_kernel(
    const float* __restrict__ Wq, const float* __restrict__ Wk,
    const float* __restrict__ Wv, const float* __restrict__ Wo,
    short* __restrict__ WqkvT, short* __restrict__ WoT) {
  __shared__ short tile[64][65];
  int z = blockIdx.z;
  const float* W = (z == 0) ? Wq : (z == 1) ? Wk : (z == 2) ? Wv : Wo;
  short* Wt = (z < 3) ? (WqkvT + (size_t)z * DD * DD) : WoT;
  int c = threadIdx.x & 63, r4 = threadIdx.x >> 6;
  int n0 = blockIdx.x << 6, k0 = blockIdx.y << 6;
#pragma unroll
  for (int p = 0; p < 16; ++p) {
    int r = (p << 2) + r4;
    tile[c][r] = f2bf(W[(size_t)(k0 + r) * DD + n0 + c]);
  }
  __syncthreads();
#pragma unroll
  for (int p = 0; p < 16; ++p) {
    int r = (p << 2) + r4;
    Wt[(size_t)(n0 + r) * DD + k0 + c] = tile[r][c];
  }
}

// ---------------- transpose V (B,S,D) bf16 head-slices -> Vt (B*H, 128, S) ----------------
__global__ __launch_bounds__(256) void transpose_v_kernel(
    const short* __restrict__ V, short* __restrict__ Vt) {
  __shared__ short tile[64][65];
  int c = threadIdx.x & 63, r4 = threadIdx.x >> 6;
  int s0 = blockIdx.x << 6, d0 = blockIdx.y << 6;
  int bh = blockIdx.z;
  int b = bh >> 4, h = bh & 15;
#pragma unroll
  for (int p = 0; p < 16; ++p) {
    int r = (p << 2) + r4;  // s-local
    tile[c][r] = V[(size_t)(b * SS + s0 + r) * DD + h * HDIM + d0 + c];
  }
  __syncthreads();
#pragma unroll
  for (int p = 0; p < 16; ++p) {
    int r = (p << 2) + r4;  // d-local
    Vt[((size_t)bh * HDIM + d0 + r) * SS + s0 + c] = tile[r][c];
  }
}

// ---------------- big-tile GEMM, frag-once (ks,mq) phases, early staging ----------------
// C(4096, ND) = A(4096,2048) * Bt(ND,2048)^T. 512 thr = 8 waves (2M x 4N).
// LDS: dbuf x (A BMx64 + B BNx64) shorts, 128-B rows, 3-bit XOR seg swizzle
// (2-way conflicts = free). Staging for tile t+1 issued at the START of tile t
// (A at phase ks0/mq0, B at ks0/mq1) into the buffer last read at t-1; the
// __syncthreads() at tile end drains loads ~3 phases (~900cy) old (cheap) and
// guards buffer swap. Frags read ONCE: B[ks] held across both mq halves.
// MODE 0: fused QKV epilogue (RoPE->Qb/Kb, plain->Vb). MODE 1: fp32 -> Cf.
template <int BM, int BN, int ND, int MODE>
__global__ __launch_bounds__(512) void gemm_big_kernel(
    const short* __restrict__ A, const short* __restrict__ Bt,
    short* __restrict__ Qb, short* __restrict__ Kb, short* __restrict__ Vb,
    float* __restrict__ Cf,
    const float* __restrict__ fc, const float* __restrict__ fs) {
  constexpr int WTM = BM / 2, WTN = BN / 4;       // wave tile
  constexpr int FM = WTM / 16, FN = WTN / 16;     // frags per wave
  constexpr int LA = BM / 64, LB = BN / 64;       // glls per thread
  constexpr int ASZ = BM * 64;                    // shorts
  constexpr int BSZ = BN * 64;
  __shared__ short smem[2][ASZ + BSZ];

  const int tid = threadIdx.x;
  const int lane = tid & 63, w = tid >> 6;
  const int cl = lane & 15, gq = lane >> 4;
  const int wm = w >> 2, wn = w & 3;

  // XCD-chunked grid: xcd owns (ND/BN/8) tn columns; B panel L2-resident.
  constexpr int TMC = 4096 / BM;
  constexpr int TNX = (ND / BN) / 8;
  const int xcd = blockIdx.x & 7, local = blockIdx.x >> 3;
  const int tm = local % TMC, tn = xcd * TNX + local / TMC;
  const int m0 = tm * BM, n0 = tn * BN;

  f32x4 acc[FM][FN];
#pragma unroll
  for (int i = 0; i < FM; ++i)
#pragma unroll
    for (int j = 0; j < FN; ++j) {
      f32x4 z = {0.f, 0.f, 0.f, 0.f};
      acc[i][j] = z;
    }

  const int srow = lane >> 3;          // 0..7 within wave's 8-row gll group
  const int sseg = lane & 7;

  auto stageA = [&](int t, int b, int j) {
    int row = j * 64 + w * 8 + srow;
    int sg = sseg ^ (row & 7);
    gll16(&A[(size_t)(m0 + row) * DD + t * 64 + sg * 8],
          &smem[b][(j * 64 + w * 8) * 64]);
  };
  auto stageB = [&](int t, int b, int j) {
    int row = j * 64 + w * 8 + srow;
    int sg = sseg ^ (row & 7);
    gll16(&Bt[(size_t)(n0 + row) * DD + t * 64 + sg * 8],
          &smem[b][ASZ + (j * 64 + w * 8) * 64]);
  };

  // prologue: stage tile 0
#pragma unroll
  for (int j = 0; j < LA; ++j) stageA(0, 0, j);
#pragma unroll
  for (int j = 0; j < LB; ++j) stageB(0, 0, j);
  __syncthreads();

  for (int t = 0; t < 32; ++t) {
    const short* Ab = smem[t & 1];
    const short* Bb = Ab + ASZ;
    const int nb = (t + 1) & 1;
    const bool more = (t + 1 < 32);
#pragma unroll
    for (int ks = 0; ks < 2; ++ks) {
      bf16x8 bh[FN];
#pragma unroll
      for (int mq = 0; mq < 2; ++mq) {
        // early staging issue for tile t+1
        if (ks == 0 && mq == 0 && more) {
#pragma unroll
          for (int j = 0; j < LA; ++j) stageA(t + 1, nb, j);
        }
        if (ks == 0 && mq == 1 && more) {
#pragma unroll
          for (int j = 0; j < LB; ++j) stageB(t + 1, nb, j);
        }
        // frag reads (A: this mq-half; B: once per ks, held across mq)
        bf16x8 af[FM / 2];
#pragma unroll
        for (int f = 0; f < FM / 2; ++f) {
          int ra = wm * WTM + mq * (WTM / 2) + f * 16 + cl;
          af[f] = *reinterpret_cast<const bf16x8*>(
              &Ab[ra * 64 + (((ks * 4 + gq) ^ (ra & 7)) << 3)]);
        }
        if (mq == 0) {
#pragma unroll
          for (int fn = 0; fn < FN; ++fn) {
            int rb = wn * WTN + fn * 16 + cl;
            bh[fn] = *reinterpret_cast<const bf16x8*>(
                &Bb[rb * 64 + (((ks * 4 + gq) ^ (rb & 7)) << 3)]);
          }
        }
        __builtin_amdgcn_s_setprio(1);
#pragma unroll
        for (int f = 0; f < FM / 2; ++f)
#pragma unroll
          for (int fn = 0; fn < FN; ++fn)
            acc[mq * (FM / 2) + f][fn] = __builtin_amdgcn_mfma_f32_16x16x32_bf16(
                af[f], bh[fn], acc[mq * (FM / 2) + f][fn], 0, 0, 0);
        __builtin_amdgcn_s_setprio(0);
      }
    }
    __syncthreads();  // drains t+1 staging (issued ~3 phases ago) + buffer swap
  }

  // ---- epilogue ----
  if constexpr (MODE == 0) {
    const int mat = tn >> 3;  // 0=Q 1=K 2=V (BN=256, 8 tn per matrix)
    const int cbase = (tn & 7) * BN + wn * WTN;
#pragma unroll
    for (int fm = 0; fm < FM; ++fm)
#pragma unroll
      for (int r = 0; r < 4; ++r) {
        int mrow = m0 + wm * WTM + fm * 16 + gq * 4 + r;
        int s = mrow & (SS - 1);
#pragma unroll
        for (int fn = 0; fn < FN; ++fn) {
          int col = cbase + fn * 16 + cl;   // 0..2047 within matrix
          float v = acc[fm][fn][r];
          if (mat < 2) {
            int c = col & 127;
            int i = c >> 1;
            float cv = fc[s * 64 + i], sv = fs[s * 64 + i];
            float vp = __shfl_xor(v, 1, 64);
            float o = (c & 1) ? (v * cv + vp * sv) : (v * cv - vp * sv);
            float qs = (mat == 0) ? 0.127517448f : 1.0f;  // log2e/sqrt(128)
            short* Dp = (mat == 0) ? Qb : Kb;
            Dp[(size_t)mrow * DD + col] = f2bf(o * qs);
          } else {
            Vb[(size_t)mrow * DD + col] = f2bf(v);
          }
        }
      }
  } else {
#pragma unroll
    for (int fm = 0; fm < FM; ++fm)
#pragma unroll
      for (int r = 0; r < 4; ++r) {
        int mrow = m0 + wm * WTM + fm * 16 + gq * 4 + r;
#pragma unroll
        for (int fn = 0; fn < FN; ++fn) {
          int ncol = n0 + wn * WTN + fn * 16 + cl;
          Cf[(size_t)mrow * ND + ncol] = acc[fm][fn][r];
        }
      }
  }
}

// ---------------- flash attention, swapped-QK^T 32x32, T3-min pipelined ----------------
// Logits arrive in base-2 units (Q pre-scaled by (1/sqrt(HD))*log2e) -> exp2f.
__global__ __launch_bounds__(256, 2) void attn_kernel(
    const short* __restrict__ Q, const short* __restrict__ K,
    const short* __restrict__ Vt, short* __restrict__ O) {
  __shared__ short Kl[2][64 * 128];
  __shared__ short Vl[2][128 * 64];
  const int id = blockIdx.x;
  const int qi = 15 - (id >> 5);
  const int bh = id & 31;
  const int b = bh >> 4, h = bh & 15;
  const int tid = threadIdx.x;
  const int lane = tid & 63, w = tid >> 6;
  const int l31 = lane & 31, hi = lane >> 5;
  const int qw = qi * 128 + w * 32;
  const int qg = qw + l31;

  const short* Kbase = K + (size_t)b * SS * DD + h * HDIM;
  const short* Vbase = Vt + (size_t)bh * HDIM * SS;
  int krow[4], kq[4], vd[4], vs[4];
#pragma unroll
  for (int i = 0; i < 4; ++i) {
    int c = w * 4 + i;
    krow[i] = c * 4 + (lane >> 4);
    kq[i] = (lane & 15) ^ (krow[i] & 7);
    vd[i] = c * 8 + (lane >> 3);
    vs[i] = (lane & 7) ^ (vd[i] & 7);
  }

  bf16x8 qf[8];
  const size_t qoff = ((size_t)b * SS + qg) * DD + h * HDIM;
#pragma unroll
  for (int s = 0; s < 8; ++s)
    qf[s] = *reinterpret_cast<const bf16x8*>(&Q[qoff + s * 16 + hi * 8]);

  f32x16 ot[4];
#pragma unroll
  for (int dt = 0; dt < 4; ++dt)
#pragma unroll
    for (int r = 0; r < 16; ++r) ot[dt][r] = 0.f;
  float m_run = -INFINITY, l_run = 0.f;

  const int NT = 2 * qi + 2;

#pragma unroll
  for (int i = 0; i < 4; ++i) {
    gll16(Kbase + (size_t)krow[i] * DD + kq[i] * 8, &Kl[0][(w * 4 + i) * 512]);
    gll16(Vbase + (size_t)vd[i] * SS + vs[i] * 8, &Vl[0][(w * 4 + i) * 512]);
  }
  __syncthreads();

  for (int t = 0; t < NT; ++t) {
    const int cur = t & 1;
    if (t + 1 < NT) {
      const int nt64 = (t + 1) * 64;
#pragma unroll
      for (int i = 0; i < 4; ++i) {
        gll16(Kbase + (size_t)(nt64 + krow[i]) * DD + kq[i] * 8,
              &Kl[cur ^ 1][(w * 4 + i) * 512]);
        gll16(Vbase + (size_t)vd[i] * SS + nt64 + vs[i] * 8,
              &Vl[cur ^ 1][(w * 4 + i) * 512]);
      }
    }

    if (t * 64 <= qw + 31) {
      const short* Kc = Kl[cur];
      const short* Vc = Vl[cur];
      f32x16 st0, st1;
#pragma unroll
      for (int r = 0; r < 16; ++r) { st0[r] = 0.f; st1[r] = 0.f; }
      __builtin_amdgcn_s_setprio(1);
#pragma unroll
      for (int s = 0; s < 8; ++s) {
        const int cs = (s * 2 + hi);
        bf16x8 kf0 = *reinterpret_cast<const bf16x8*>(
            &Kc[l31 * 128 + ((cs ^ (l31 & 7)) << 3)]);
        st0 = __builtin_amdgcn_mfma_f32_32x32x16_bf16(kf0, qf[s], st0, 0, 0, 0);
        bf16x8 kf1 = *reinterpret_cast<const bf16x8*>(
            &Kc[(32 + l31) * 128 + ((cs ^ (l31 & 7)) << 3)]);
        st1 = __builtin_amdgcn_mfma_f32_32x32x16_bf16(kf1, qf[s], st1, 0, 0, 0);
      }
      __builtin_amdgcn_s_setprio(0);
      if (t * 64 + 63 > qw) {
#pragma unroll
        for (int r = 0; r < 16; ++r) {
          int dl = (r & 3) + 8 * (r >> 2) + 4 * hi;
          if (t * 64 + dl > qg) st0[r] = -1e30f;
          if (t * 64 + 32 + dl > qg) st1[r] = -1e30f;
        }
      }
      // ---- online softmax (base-2), tree reductions, defer-max ----
      float mx[16];
#pragma unroll
      for (int r = 0; r < 16; ++r) mx[r] = fmaxf(st0[r], st1[r]);
#pragma unroll
      for (int off = 8; off >= 1; off >>= 1)
#pragma unroll
        for (int r = 0; r < 8; ++r)
          if (r < off) mx[r] = fmaxf(mx[r], mx[r + off]);
      float pm = mx[0];
      {
        auto sw = __builtin_amdgcn_permlane32_swap(asi(pm), asi(pm), false, false);
        pm = fmaxf(asf(sw[0]), asf(sw[1]));
      }
      if (!__all(pm <= m_run + 11.5f)) {
        float mn = fmaxf(m_run, pm);
        float al = exp2f(m_run - mn);
        m_run = mn;
        l_run *= al;
#pragma unroll
        for (int dt = 0; dt < 4; ++dt)
#pragma unroll
          for (int r = 0; r < 16; ++r) ot[dt][r] *= al;
      }
#pragma unroll
      for (int r = 0; r < 16; ++r) st0[r] = exp2f(st0[r] - m_run);
#pragma unroll
      for (int r = 0; r < 16; ++r) st1[r] = exp2f(st1[r] - m_run);
      float sm[16];
#pragma unroll
      for (int r = 0; r < 16; ++r) sm[r] = st0[r] + st1[r];
#pragma unroll
      for (int off = 8; off >= 1; off >>= 1)
#pragma unroll
        for (int r = 0; r < 8; ++r)
          if (r < off) sm[r] += sm[r + off];
      float ps = sm[0];
      {
        auto sw = __builtin_amdgcn_permlane32_swap(asi(ps), asi(ps), false, false);
        ps = asf(sw[0]) + asf(sw[1]);
      }
      l_run += ps;

      // ---- pack P -> bf16 B-frags via cvt_pk + permlane32_swap (T12) ----
      bf16x8 pf[4];
#pragma unroll
      for (int s = 0; s < 4; ++s) {
        float e0, e1, e2, e3, e4, e5, e6, e7;
        if (s < 2) {
          e0 = st0[8 * s + 0]; e1 = st0[8 * s + 1]; e2 = st0[8 * s + 2]; e3 = st0[8 * s + 3];
          e4 = st0[8 * s + 4]; e5 = st0[8 * s + 5]; e6 = st0[8 * s + 6]; e7 = st0[8 * s + 7];
        } else {
          e0 = st1[8 * (s - 2) + 0]; e1 = st1[8 * (s - 2) + 1]; e2 = st1[8 * (s - 2) + 2]; e3 = st1[8 * (s - 2) + 3];
          e4 = st1[8 * (s - 2) + 4]; e5 = st1[8 * (s - 2) + 5]; e6 = st1[8 * (s - 2) + 6]; e7 = st1[8 * (s - 2) + 7];
        }
        unsigned a0 = cvtpk_bf16(e0, e1);
        unsigned a1 = cvtpk_bf16(e2, e3);
        unsigned b0 = cvtpk_bf16(e4, e5);
        unsigned b1 = cvtpk_bf16(e6, e7);
        auto r0 = __builtin_amdgcn_permlane32_swap((int)a0, (int)b0, false, false);
        auto r1 = __builtin_amdgcn_permlane32_swap((int)a1, (int)b1, false, false);
        union { int u[4]; bf16x8 v; } pk;
        pk.u[0] = r0[0]; pk.u[1] = r1[0]; pk.u[2] = r0[1]; pk.u[3] = r1[1];
        pf[s] = pk.v;
      }

      __builtin_amdgcn_s_setprio(1);
#pragma unroll
      for (int dt = 0; dt < 4; ++dt) {
        const int vr = dt * 32 + l31;
#pragma unroll
        for (int s = 0; s < 4; ++s) {
          bf16x8 vf = *reinterpret_cast<const bf16x8*>(
              &Vc[vr * 64 + (((s * 2 + hi) ^ (vr & 7)) << 3)]);
          ot[dt] = __builtin_amdgcn_mfma_f32_32x32x16_bf16(vf, pf[s], ot[dt], 0, 0, 0);
        }
      }
      __builtin_amdgcn_s_setprio(0);
    }
    __syncthreads();
  }

  float inv = 1.0f / l_run;
  const size_t orow = ((size_t)b * SS + qg) * DD + h * HDIM;
#pragma unroll
  for (int dt = 0; dt < 4; ++dt)
#pragma unroll
    for (int g = 0; g < 4; ++g) {
      bf16x4 v;
#pragma unroll
      for (int k = 0; k < 4; ++k) v[k] = f2bf(ot[dt][4 * g + k] * inv);
      *reinterpret_cast<bf16x4*>(&O[orow + dt * 32 + 8 * g + 4 * hi]) = v;
    }
}

extern "C" void kernel_launch(void* const* d_in, const int* in_sizes, int n_in,
                              void* d_out, int out_size, void* d_ws, size_t ws_size,
                              hipStream_t stream) {
  const float* x = (const float*)d_in[0];
  const float* Wq = (const float*)d_in[1];
  const float* Wk = (const float*)d_in[2];
  const float* Wv = (const float*)d_in[3];
  const float* Wo = (const float*)d_in[4];
  const float* fc = (const float*)d_in[5];
  const float* fs = (const float*)d_in[6];
  float* out = (float*)d_out;
  char* ws = (char*)d_ws;

  short* xb     = (short*)(ws + 0);                      // 16MB; reused as attn_out
  short* WqkvT  = (short*)(ws + (size_t)16 * 1048576);   // 24MB; reused as VtB
  short* WoT    = (short*)(ws + (size_t)40 * 1048576);   // 8MB
  short* Qb     = (short*)(ws + (size_t)48 * 1048576);   // 16MB
  short* Kb     = (short*)(ws + (size_t)64 * 1048576);   // 16MB
  short* Vb     = (short*)(ws + (size_t)80 * 1048576);   // 16MB (plain V)
  short* VtB    = WqkvT;                                 // alias (dead after qkv gemm)

  cast_bf16_kernel<<<8192, 256, 0, stream>>>(x, xb, 2097152);
  transpose4_kernel<<<dim3(32, 32, 4), 256, 0, stream>>>(Wq, Wk, Wv, Wo, WqkvT, WoT);

  gemm_big_kernel<256, 256, 6144, 0><<<384, 512, 0, stream>>>(
      xb, WqkvT, Qb, Kb, Vb, nullptr, fc, fs);

  transpose_v_kernel<<<dim3(32, 2, 32), 256, 0, stream>>>(Vb, VtB);

  attn_kernel<<<512, 256, 0, stream>>>(Qb, Kb, VtB, xb);  // attn_out = xb

  gemm_big_kernel<128, 256, 2048, 1><<<256, 512, 0, stream>>>(
      xb, WoT, nullptr, nullptr, nullptr, out, nullptr, nullptr);
}